// Round 8
// baseline (188.346 us; speedup 1.0000x reference)
//
#include <hip/hip_runtime.h>
#include <float.h>
#include <math.h>

#define NB 128
#define NQ 16
#define ND 800
#define NE 300

// workspace layout (float offsets). All regions written every call.
#define WS_SIM    0                          // [NB][NQ][ND] raw dots (= cosine, unit rows)
#define WS_CTXINV (NB*NQ*ND)                 // [NB][ND] 1/(||ctx||/9+1e-9)
#define WS_SCORES (WS_CTXINV + NB*ND)        // [NB][NQ][13] (slot 12 = idf)
#define WS_QBF    (WS_SCORES + NB*NQ*13)     // [NB][16][320] bf16 (q, zero-padded K)

#define SP 308                                // kfused LDS row pitch (floats)
#define TP 804                                // ktail LDS sim pitch (floats)

typedef __attribute__((ext_vector_type(8))) short short8;
typedef __attribute__((ext_vector_type(4))) float f32x4;
typedef __attribute__((ext_vector_type(4))) unsigned short ushort4v;

__device__ __forceinline__ unsigned short f2bf(float x) {   // RNE fp32->bf16
    unsigned u = __float_as_uint(x);
    u += 0x7FFF + ((u >> 16) & 1);
    return (unsigned short)(u >> 16);
}

__device__ __forceinline__ void ins6(float t[6], float v) {
    if (v > t[5]) t[5] = v;
    float a;
    if (t[5] > t[4]) { a = t[4]; t[4] = t[5]; t[5] = a; }
    if (t[4] > t[3]) { a = t[3]; t[3] = t[4]; t[4] = a; }
    if (t[3] > t[2]) { a = t[2]; t[2] = t[3]; t[3] = a; }
    if (t[2] > t[1]) { a = t[1]; t[1] = t[2]; t[2] = a; }
    if (t[1] > t[0]) { a = t[0]; t[0] = t[1]; t[1] = a; }
}

__device__ __forceinline__ void ins2(float& a1, float& a2, float v) {
    if (v > a2) a2 = v;
    if (a2 > a1) { float t = a1; a1 = a2; a2 = t; }
}

__device__ __forceinline__ void merge2(float& a1, float& a2, float b1v, float b2v) {
    float hi = fmaxf(a1, b1v), lo = fminf(a1, b1v);
    a1 = hi;
    a2 = fmaxf(lo, fmaxf(a2, b2v));
}

// sliding sum of 8 consecutive lanes (this lane .. lane+7)
__device__ __forceinline__ float slide8(float s) {
    s += __shfl_down(s, 1);
    s += __shfl_down(s, 2);
    s += __shfl_down(s, 4);
    return s;
}

// ------- kq: q rows -> bf16 [16][320] (K-pad zeroed) + idf -------
__global__ __launch_bounds__(256) void kq(const int* __restrict__ qrls,
                                          const float* __restrict__ emb,
                                          const float* __restrict__ idf,
                                          float* __restrict__ ws) {
    int b = blockIdx.x;
    int tid = threadIdx.x;
    __shared__ int qrow[16];
    if (tid < 16) qrow[tid] = qrls[b * NQ + tid];
    __syncthreads();
    unsigned short* qbf = (unsigned short*)(ws + WS_QBF) + (size_t)b * 16 * 320;
    // 16 rows x 75 float4 copies (fp32 -> bf16)
    for (int it = tid; it < 1200; it += 256) {
        int q = it / 75, e4 = it - q * 75;
        float4 v = *(const float4*)(emb + (size_t)qrow[q] * NE + e4 * 4);
        ushort4v u;
        u[0] = f2bf(v.x); u[1] = f2bf(v.y); u[2] = f2bf(v.z); u[3] = f2bf(v.w);
        *(ushort4v*)(qbf + q * 320 + e4 * 4) = u;
    }
    // K-pad elems 300..319 -> 0
    if (tid < 160) {
        int q = tid / 10, p = tid - q * 10;
        *(unsigned*)(qbf + q * 320 + 300 + p * 2) = 0u;
    }
    if (tid < NQ)
        ws[WS_SCORES + (b * NQ + tid) * 13 + 12] = idf[qrow[tid]];
}

// ------- kfused: grid (25, NB), 256 thr = 4 waves -------
// Stage 40 doc rows (32-col tile + 4-row halo) fp32 via global_load_lds
// (async, per-lane gather src, linear LDS dest). Then:
//   waves 0,1: MFMA 16q x 16d (fp32 LDS -> bf16 frags at read time)
//   waves 2,3: ctx-norm (split by seg halves, combined via LDS)
__global__ __launch_bounds__(256, 3) void kfused(const int* __restrict__ docw,
                                                 const float* __restrict__ emb,
                                                 float* __restrict__ ws) {
    int b = blockIdx.y;
    int base = blockIdx.x * 32;
    int tid = threadIdx.x;
    __shared__ float slds[12544];           // 49 glds-chunks x 1KB
    __shared__ int sidx[40];
    __shared__ float sqp[2][40];

    int wv = tid >> 6, lane = tid & 63;

    if (tid < 40) {
        int rg = base - 4 + tid;
        sidx[tid] = (rg >= 0 && rg < ND) ? docw[b * ND + rg] : -1;
    }
    __syncthreads();

    // ---- async staging: 49 x 1KB, waves issue disjoint chunks ----
    for (int j = wv; j < 49; j += 4) {
        int jj = __builtin_amdgcn_readfirstlane(j);
        int f = jj * 64 + lane;              // flat 16B chunk id
        int r = f / 77;                      // staged row (pitch 308 = 77 chunks)
        int cs = f - r * 77;                 // chunk within row
        int rr = (r < 40) ? r : 39;
        int idx = sidx[rr];
        int c = (cs < 75) ? cs : 74;         // clamp pad chunks to valid addr
        const float* gp = emb + (size_t)((idx < 0) ? 0 : idx) * NE + c * 4;
        __builtin_amdgcn_global_load_lds(
            (const __attribute__((address_space(1))) void*)gp,
            (__attribute__((address_space(3))) void*)&slds[jj * 256],
            16, 0, 0);
    }
    __syncthreads();                         // drains vmcnt + barrier

    // ---- zero pad chunks (cols 300..307) and invalid halo rows ----
    float4 z4 = {0.f, 0.f, 0.f, 0.f};
    if (tid < 80) {
        int r = tid >> 1, c = 75 + (tid & 1);
        *(float4*)&slds[r * SP + c * 4] = z4;
    }
    for (int t = tid; t < 40 * 75; t += 256) {
        int r = t / 75;
        if (sidx[r] < 0) {
            int c = t - r * 75;
            *(float4*)&slds[r * SP + c * 4] = z4;
        }
    }
    __syncthreads();

    int rsub = lane & 15, kgrp = lane >> 4;

    if (wv < 2) {
        // ---- MFMA: cols base + wv*16 + rsub, all 16 q, K=320 ----
        const unsigned short* qp = (const unsigned short*)(ws + WS_QBF)
                                   + ((size_t)b * 16 + rsub) * 320 + kgrp * 8;
        short8 afr[10];
#pragma unroll
        for (int k = 0; k < 10; ++k)
            afr[k] = *(const short8*)(qp + k * 32);

        int lrb = (4 + wv * 16 + rsub) * SP;
        f32x4 acc = {0.f, 0.f, 0.f, 0.f};
#pragma unroll
        for (int k = 0; k < 10; ++k) {
            int c0 = k * 32 + kgrp * 8;
            short8 bf = {0, 0, 0, 0, 0, 0, 0, 0};
            if (c0 < 300) {                  // c0=296 reads zeroed pad 300..303
                float4 x0 = *(const float4*)&slds[lrb + c0];
                float4 x1 = *(const float4*)&slds[lrb + c0 + 4];
                bf[0] = (short)f2bf(x0.x); bf[1] = (short)f2bf(x0.y);
                bf[2] = (short)f2bf(x0.z); bf[3] = (short)f2bf(x0.w);
                bf[4] = (short)f2bf(x1.x); bf[5] = (short)f2bf(x1.y);
                bf[6] = (short)f2bf(x1.z); bf[7] = (short)f2bf(x1.w);
            }
            acc = __builtin_amdgcn_mfma_f32_16x16x32_bf16(afr[k], bf, acc, 0, 0, 0);
        }
        int col = base + wv * 16 + rsub;
        float* simp = ws + WS_SIM + (size_t)b * NQ * ND + col;
#pragma unroll
        for (int i = 0; i < 4; ++i)
            simp[(size_t)(kgrp * 4 + i) * ND] = acc[i];
    } else {
        // ---- ctx-norm: wave 2 segs 0..18, wave 3 segs 19..37 ----
        int half = wv - 2;
        float sq = 0.f;
        for (int seg = half * 19; seg < half * 19 + 19; ++seg) {
            float xs[8];
            if (lane < 40) {
                float4 x0 = *(const float4*)&slds[lane * SP + seg * 8];
                float4 x1 = *(const float4*)&slds[lane * SP + seg * 8 + 4];
                xs[0] = x0.x; xs[1] = x0.y; xs[2] = x0.z; xs[3] = x0.w;
                xs[4] = x1.x; xs[5] = x1.y; xs[6] = x1.z; xs[7] = x1.w;
            } else {
#pragma unroll
                for (int e = 0; e < 8; ++e) xs[e] = 0.f;
            }
#pragma unroll
            for (int e = 0; e < 8; ++e) {
                float s = slide8(xs[e]);
                sq = fmaf(s, s, sq);
            }
        }
        if (lane < 40) sqp[half][lane] = sq;
    }
    __syncthreads();
    if (wv == 2 && lane < 32) {
        float st = sqp[0][lane] + sqp[1][lane];
        ws[WS_CTXINV + b * ND + base + lane] =
            1.f / (sqrtf(st) * (1.f / 9.f) + 1e-9f);
    }
}

// ------- ktail: fused conv + ctx-top6 + MLP; grid (NB), 512 thr -------
__global__ __launch_bounds__(512) void ktail(const float* __restrict__ c1w,
                                             const float* __restrict__ c1b,
                                             const float* __restrict__ c2w,
                                             const float* __restrict__ c2b,
                                             const float* __restrict__ c3w,
                                             const float* __restrict__ c3b,
                                             const float* __restrict__ w1,
                                             const float* __restrict__ b1,
                                             const float* __restrict__ w2,
                                             const float* __restrict__ b2,
                                             const float* __restrict__ w3,
                                             const float* __restrict__ b3,
                                             float* __restrict__ ws,
                                             float* __restrict__ out) {
    int b = blockIdx.x;
    int tid = threadIdx.x;
    __shared__ float SM[18 * TP];       // sim rows (later: in-place prefix)
    __shared__ float PART[8][16][6];
    __shared__ float sc[208];
    __shared__ float h[32];

    float4 z4 = {0.f, 0.f, 0.f, 0.f};
    const float* simb = ws + WS_SIM + (size_t)b * NQ * ND;
    for (int it = tid; it < 3200; it += 512) {
        int q = it / 200, c4 = it - q * 200;
        *(float4*)&SM[q * TP + c4 * 4] = *(const float4*)(simb + (size_t)q * ND + c4 * 4);
    }
    for (int it = tid; it < 402; it += 512) {      // zero rows 16,17
        int r = 16 + it / 201, c4 = it % 201;
        *(float4*)&SM[r * TP + c4 * 4] = z4;
    }
    if (tid < 16) *(float4*)&SM[tid * TP + 800] = z4;  // col halo rows 0..15
    __syncthreads();

    // ---- conv phase: 16q x 32 d-groups, 25 cells each ----
    int q = tid & 15, dg = tid >> 4;    // dg 0..31
    float a1[3] = {-FLT_MAX, -FLT_MAX, -FLT_MAX};
    float a2[3] = {-FLT_MAX, -FLT_MAX, -FLT_MAX};
    for (int j = 0; j < 25; ++j) {
        int d = dg + 32 * j;
        float s00 = SM[q * TP + d],       s01 = SM[q * TP + d + 1],       s02 = SM[q * TP + d + 2];
        float s10 = SM[(q+1) * TP + d],   s11 = SM[(q+1) * TP + d + 1],   s12 = SM[(q+1) * TP + d + 2];
        float s20 = SM[(q+2) * TP + d],   s21 = SM[(q+2) * TP + d + 1],   s22 = SM[(q+2) * TP + d + 2];
        float m1 = -FLT_MAX, m2 = -FLT_MAX, m3 = -FLT_MAX;
        for (int f = 0; f < 32; ++f) {   // uniform scalar weight loads
            float v1 = c1w[f] * s00 + c1b[f];
            m1 = fmaxf(m1, v1);
            float v2 = c2b[f] + c2w[f*4+0]*s00 + c2w[f*4+1]*s01
                              + c2w[f*4+2]*s10 + c2w[f*4+3]*s11;
            m2 = fmaxf(m2, v2);
            float v3 = c3b[f] + c3w[f*9+0]*s00 + c3w[f*9+1]*s01 + c3w[f*9+2]*s02
                              + c3w[f*9+3]*s10 + c3w[f*9+4]*s11 + c3w[f*9+5]*s12
                              + c3w[f*9+6]*s20 + c3w[f*9+7]*s21 + c3w[f*9+8]*s22;
            m3 = fmaxf(m3, v3);
        }
        m1 = fmaxf(m1, 0.f); m2 = fmaxf(m2, 0.f); m3 = fmaxf(m3, 0.f);
        ins2(a1[0], a2[0], m1); ins2(a1[1], a2[1], m2); ins2(a1[2], a2[2], m3);
    }
    int wv = tid >> 6, lane = tid & 63;
#pragma unroll
    for (int m = 16; m <= 32; m <<= 1) {           // merge same-q lanes in wave
#pragma unroll
        for (int ng = 0; ng < 3; ++ng) {
            float b1v = __shfl_xor(a1[ng], m), b2v = __shfl_xor(a2[ng], m);
            merge2(a1[ng], a2[ng], b1v, b2v);
        }
    }
    if (lane < 16) {
#pragma unroll
        for (int ng = 0; ng < 3; ++ng) {
            PART[wv][lane][ng * 2]     = a1[ng];
            PART[wv][lane][ng * 2 + 1] = a2[ng];
        }
    }
    __syncthreads();
    if (tid < 16) {
#pragma unroll
        for (int ng = 0; ng < 3; ++ng) {
            float x1 = PART[0][tid][ng * 2], x2 = PART[0][tid][ng * 2 + 1];
#pragma unroll
            for (int p = 1; p < 8; ++p)
                merge2(x1, x2, PART[p][tid][ng * 2], PART[p][tid][ng * 2 + 1]);
            sc[tid * 13 + ng * 2] = x1; sc[tid * 13 + ng * 2 + 1] = x2;
        }
    } else if (tid < 32) {
        int q2 = tid - 16;
        sc[q2 * 13 + 12] = ws[WS_SCORES + (size_t)(b * NQ + q2) * 13 + 12];
    }

    // ---- prefix scan (in place) + top6: wave wv owns rows 2wv, 2wv+1 ----
    const float* cinv = ws + WS_CTXINV + (size_t)b * ND;
    for (int rr = 0; rr < 2; ++rr) {
        int qq = wv * 2 + rr;
        float* P = &SM[qq * TP];
        float carry = 0.f;
        for (int c = 0; c < 13; ++c) {
            int d = c * 64 + lane;
            float v = (d < ND) ? P[d] : 0.f;
#pragma unroll
            for (int off = 1; off < 64; off <<= 1) {
                float t = __shfl_up(v, off);
                if (lane >= off) v += t;
            }
            v += carry;
            if (d < ND) P[d] = v;
            carry = __shfl(v, 63);
        }
        float top[6] = {-FLT_MAX,-FLT_MAX,-FLT_MAX,-FLT_MAX,-FLT_MAX,-FLT_MAX};
        for (int c = 0; c < 13; ++c) {
            int d = c * 64 + lane;
            if (d < ND) {
                int hi_i = (d + 3 < ND) ? d + 3 : ND - 1;
                float hi = P[hi_i];
                float lo = (d >= 5) ? P[d - 5] : 0.f;
                float ctx = (hi - lo) * (1.f / 9.f) * cinv[d];
                ins6(top, ctx);
            }
        }
#pragma unroll
        for (int m = 1; m < 64; m <<= 1) {
            float o0 = __shfl_xor(top[0], m), o1 = __shfl_xor(top[1], m);
            float o2 = __shfl_xor(top[2], m), o3 = __shfl_xor(top[3], m);
            float o4 = __shfl_xor(top[4], m), o5 = __shfl_xor(top[5], m);
            ins6(top, o0); ins6(top, o1); ins6(top, o2);
            ins6(top, o3); ins6(top, o4); ins6(top, o5);
        }
        if (lane == 0) {
            sc[qq * 13 + 6]  = top[0]; sc[qq * 13 + 7]  = top[1];
            sc[qq * 13 + 8]  = top[2]; sc[qq * 13 + 9]  = top[3];
            sc[qq * 13 + 10] = top[4]; sc[qq * 13 + 11] = top[5];
        }
    }
    __syncthreads();

    // ---- MLP: wave 0 only ----
    if (tid < 64) {
        int j = tid & 31, half = tid >> 5;
        float a = 0.f;
        int i0 = half * 104;
        for (int i = 0; i < 104; ++i) a += sc[i0 + i] * w1[(i0 + i) * 32 + j];
        a += __shfl_xor(a, 32);
        a = fmaxf(a + b1[j], 0.f);
        if (half == 0) h[j] = a;
        __builtin_amdgcn_s_barrier();   // wave-level; all 64 lanes present
        float r = 0.f;
        if (half == 0) {
            float a2v = 0.f;
            for (int k = 0; k < 32; ++k) a2v += h[k] * w2[k * 32 + j];
            a2v = fmaxf(a2v + b2[j], 0.f);
            r = a2v * w3[j];
        }
#pragma unroll
        for (int m = 1; m <= 32; m <<= 1) r += __shfl_xor(r, m);
        if (tid == 0) out[b] = r + b3[0];
    }
}

extern "C" void kernel_launch(void* const* d_in, const int* in_sizes, int n_in,
                              void* d_out, int out_size, void* d_ws, size_t ws_size,
                              hipStream_t stream) {
    (void)in_sizes; (void)n_in; (void)out_size; (void)ws_size;
    const int*   qrls = (const int*)d_in[0];
    const int*   docw = (const int*)d_in[1];
    const float* emb  = (const float*)d_in[2];
    const float* idf  = (const float*)d_in[3];
    const float* c1w  = (const float*)d_in[4];
    const float* c1b  = (const float*)d_in[5];
    const float* c2w  = (const float*)d_in[6];
    const float* c2b  = (const float*)d_in[7];
    const float* c3w  = (const float*)d_in[8];
    const float* c3b  = (const float*)d_in[9];
    const float* w1   = (const float*)d_in[10];
    const float* b1   = (const float*)d_in[11];
    const float* w2   = (const float*)d_in[12];
    const float* b2   = (const float*)d_in[13];
    const float* w3   = (const float*)d_in[14];
    const float* b3   = (const float*)d_in[15];
    float* ws  = (float*)d_ws;
    float* out = (float*)d_out;

    kq<<<dim3(NB), 256, 0, stream>>>(qrls, emb, idf, ws);
    kfused<<<dim3(25, NB), 256, 0, stream>>>(docw, emb, ws);
    ktail<<<dim3(NB), 512, 0, stream>>>(c1w, c1b, c2w, c2b, c3w, c3b,
                                        w1, b1, w2, b2, w3, b3, ws, out);
}

// Round 9
// 130.209 us; speedup vs baseline: 1.4465x; 1.4465x over previous
//
#include <hip/hip_runtime.h>
#include <float.h>
#include <math.h>

#define NB 128
#define NQ 16
#define ND 800
#define NE 300

// workspace layout (float offsets). All regions written every call.
#define WS_SIM    0                          // [NB][NQ][ND] raw dots (= cosine, unit rows)
#define WS_CTXINV (NB*NQ*ND)                 // [NB][ND] 1/(||ctx||/9+1e-9)
#define WS_SCORES (WS_CTXINV + NB*ND)        // [NB][NQ][13] (slot 12 = idf)
#define WS_C2     (WS_SCORES + NB*NQ*13)     // [NB][NQ][3][7 strips][2] partial top2
#define WS_QBF    (WS_C2 + NB*NQ*3*14)       // [NB][16][320] bf16 (q, zero-padded K)

#define SP 308                                // kfused LDS row pitch (floats)

typedef __attribute__((ext_vector_type(8))) short short8;
typedef __attribute__((ext_vector_type(4))) float f32x4;
typedef __attribute__((ext_vector_type(4))) unsigned short ushort4v;

__device__ __forceinline__ unsigned short f2bf(float x) {   // RNE fp32->bf16
    unsigned u = __float_as_uint(x);
    u += 0x7FFF + ((u >> 16) & 1);
    return (unsigned short)(u >> 16);
}

__device__ __forceinline__ void ins6(float t[6], float v) {
    if (v > t[5]) t[5] = v;
    float a;
    if (t[5] > t[4]) { a = t[4]; t[4] = t[5]; t[5] = a; }
    if (t[4] > t[3]) { a = t[3]; t[3] = t[4]; t[4] = a; }
    if (t[3] > t[2]) { a = t[2]; t[2] = t[3]; t[3] = a; }
    if (t[2] > t[1]) { a = t[1]; t[1] = t[2]; t[2] = a; }
    if (t[1] > t[0]) { a = t[0]; t[0] = t[1]; t[1] = a; }
}

__device__ __forceinline__ void ins2(float& a1, float& a2, float v) {
    if (v > a2) a2 = v;
    if (a2 > a1) { float t = a1; a1 = a2; a2 = t; }
}

__device__ __forceinline__ void merge2(float& a1, float& a2, float b1v, float b2v) {
    float hi = fmaxf(a1, b1v), lo = fminf(a1, b1v);
    a1 = hi;
    a2 = fmaxf(lo, fmaxf(a2, b2v));
}

// sliding sum of 8 consecutive lanes (this lane .. lane+7)
__device__ __forceinline__ float slide8(float s) {
    s += __shfl_down(s, 1);
    s += __shfl_down(s, 2);
    s += __shfl_down(s, 4);
    return s;
}

// ------- kq: q rows -> bf16 [16][320] (K-pad zeroed) + idf -------
__global__ __launch_bounds__(256) void kq(const int* __restrict__ qrls,
                                          const float* __restrict__ emb,
                                          const float* __restrict__ idf,
                                          float* __restrict__ ws) {
    int b = blockIdx.x;
    int tid = threadIdx.x;
    __shared__ int qrow[16];
    if (tid < 16) qrow[tid] = qrls[b * NQ + tid];
    __syncthreads();
    unsigned short* qbf = (unsigned short*)(ws + WS_QBF) + (size_t)b * 16 * 320;
    for (int it = tid; it < 1200; it += 256) {
        int q = it / 75, e4 = it - q * 75;
        float4 v = *(const float4*)(emb + (size_t)qrow[q] * NE + e4 * 4);
        ushort4v u;
        u[0] = f2bf(v.x); u[1] = f2bf(v.y); u[2] = f2bf(v.z); u[3] = f2bf(v.w);
        *(ushort4v*)(qbf + q * 320 + e4 * 4) = u;
    }
    if (tid < 160) {
        int q = tid / 10, p = tid - q * 10;
        *(unsigned*)(qbf + q * 320 + 300 + p * 2) = 0u;
    }
    if (tid < NQ)
        ws[WS_SCORES + (b * NQ + tid) * 13 + 12] = idf[qrow[tid]];
}

// ------- kfused: grid (25, NB), 256 thr = 4 waves -------
// Stage 40 doc rows (32-col tile + 4-row halo) fp32 via global_load_lds.
// waves 0,1: MFMA 16q x 16d; waves 2,3: ctx-norm halves.
__global__ __launch_bounds__(256, 3) void kfused(const int* __restrict__ docw,
                                                 const float* __restrict__ emb,
                                                 float* __restrict__ ws) {
    int b = blockIdx.y;
    int base = blockIdx.x * 32;
    int tid = threadIdx.x;
    __shared__ float slds[12544];           // 49 glds-chunks x 1KB
    __shared__ int sidx[40];
    __shared__ float sqp[2][40];

    int wv = tid >> 6, lane = tid & 63;

    if (tid < 40) {
        int rg = base - 4 + tid;
        sidx[tid] = (rg >= 0 && rg < ND) ? docw[b * ND + rg] : -1;
    }
    __syncthreads();

    for (int j = wv; j < 49; j += 4) {
        int jj = __builtin_amdgcn_readfirstlane(j);
        int f = jj * 64 + lane;
        int r = f / 77;
        int cs = f - r * 77;
        int rr = (r < 40) ? r : 39;
        int idx = sidx[rr];
        int c = (cs < 75) ? cs : 74;
        const float* gp = emb + (size_t)((idx < 0) ? 0 : idx) * NE + c * 4;
        __builtin_amdgcn_global_load_lds(
            (const __attribute__((address_space(1))) void*)gp,
            (__attribute__((address_space(3))) void*)&slds[jj * 256],
            16, 0, 0);
    }
    __syncthreads();

    float4 z4 = {0.f, 0.f, 0.f, 0.f};
    if (tid < 80) {
        int r = tid >> 1, c = 75 + (tid & 1);
        *(float4*)&slds[r * SP + c * 4] = z4;
    }
    for (int t = tid; t < 40 * 75; t += 256) {
        int r = t / 75;
        if (sidx[r] < 0) {
            int c = t - r * 75;
            *(float4*)&slds[r * SP + c * 4] = z4;
        }
    }
    __syncthreads();

    int rsub = lane & 15, kgrp = lane >> 4;

    if (wv < 2) {
        const unsigned short* qp = (const unsigned short*)(ws + WS_QBF)
                                   + ((size_t)b * 16 + rsub) * 320 + kgrp * 8;
        short8 afr[10];
#pragma unroll
        for (int k = 0; k < 10; ++k)
            afr[k] = *(const short8*)(qp + k * 32);

        int lrb = (4 + wv * 16 + rsub) * SP;
        f32x4 acc = {0.f, 0.f, 0.f, 0.f};
#pragma unroll
        for (int k = 0; k < 10; ++k) {
            int c0 = k * 32 + kgrp * 8;
            short8 bf = {0, 0, 0, 0, 0, 0, 0, 0};
            if (c0 < 300) {
                float4 x0 = *(const float4*)&slds[lrb + c0];
                float4 x1 = *(const float4*)&slds[lrb + c0 + 4];
                bf[0] = (short)f2bf(x0.x); bf[1] = (short)f2bf(x0.y);
                bf[2] = (short)f2bf(x0.z); bf[3] = (short)f2bf(x0.w);
                bf[4] = (short)f2bf(x1.x); bf[5] = (short)f2bf(x1.y);
                bf[6] = (short)f2bf(x1.z); bf[7] = (short)f2bf(x1.w);
            }
            acc = __builtin_amdgcn_mfma_f32_16x16x32_bf16(afr[k], bf, acc, 0, 0, 0);
        }
        int col = base + wv * 16 + rsub;
        float* simp = ws + WS_SIM + (size_t)b * NQ * ND + col;
#pragma unroll
        for (int i = 0; i < 4; ++i)
            simp[(size_t)(kgrp * 4 + i) * ND] = acc[i];
    } else {
        int half = wv - 2;
        float sq = 0.f;
        for (int seg = half * 19; seg < half * 19 + 19; ++seg) {
            float xs[8];
            if (lane < 40) {
                float4 x0 = *(const float4*)&slds[lane * SP + seg * 8];
                float4 x1 = *(const float4*)&slds[lane * SP + seg * 8 + 4];
                xs[0] = x0.x; xs[1] = x0.y; xs[2] = x0.z; xs[3] = x0.w;
                xs[4] = x1.x; xs[5] = x1.y; xs[6] = x1.z; xs[7] = x1.w;
            } else {
#pragma unroll
                for (int e = 0; e < 8; ++e) xs[e] = 0.f;
            }
#pragma unroll
            for (int e = 0; e < 8; ++e) {
                float s = slide8(xs[e]);
                sq = fmaf(s, s, sq);
            }
        }
        if (lane < 40) sqp[half][lane] = sq;
    }
    __syncthreads();
    if (wv == 2 && lane < 32) {
        float st = sqp[0][lane] + sqp[1][lane];
        ws[WS_CTXINV + b * ND + base + lane] =
            1.f / (sqrtf(st) * (1.f / 9.f) + 1e-9f);
    }
}

// ------- kconv2: f-outer conv; grid (7, NB), 256 thr -------
// Thread (q, dt): 8 cells at d = strip*128 + dt*8 + i. Inputs (3 rows x 10
// cols) live in registers; 32-filter loop amortizes 17 uniform s_loads over
// 136 FMAs. Per-strip top2 -> WS_C2[b][q][ng][strip][2].
__global__ __launch_bounds__(256) void kconv2(const float* __restrict__ c1w,
                                              const float* __restrict__ c1b,
                                              const float* __restrict__ c2w,
                                              const float* __restrict__ c2b,
                                              const float* __restrict__ c3w,
                                              const float* __restrict__ c3b,
                                              float* __restrict__ ws) {
    int b = blockIdx.y;
    int strip = blockIdx.x;            // 0..6, 128 cells each (covers 0..895)
    int c0 = strip * 128;
    int tid = threadIdx.x;
    __shared__ float S[18][132];       // rows 16,17 zero; 130 cols used
    for (int idx = tid; idx < 18 * 130; idx += 256) {
        int r = idx / 130, c = idx % 130;
        int d = c0 + c;
        float v = 0.f;
        if (r < NQ && d < ND) v = ws[WS_SIM + (size_t)(b * NQ + r) * ND + d];
        S[r][c] = v;
    }
    __syncthreads();

    int q = tid & 15, dt = tid >> 4;   // dt 0..15
    int cb = dt * 8;
    float s0[10], s1[10], s2[10];
#pragma unroll
    for (int i = 0; i < 10; ++i) {
        s0[i] = S[q][cb + i];
        s1[i] = S[q + 1][cb + i];
        s2[i] = S[q + 2][cb + i];
    }
    float m1[8], m2[8], m3[8];
#pragma unroll
    for (int i = 0; i < 8; ++i) { m1[i] = -FLT_MAX; m2[i] = -FLT_MAX; m3[i] = -FLT_MAX; }

    for (int f = 0; f < 32; ++f) {
        float w1f = c1w[f], b1f = c1b[f];
        float w20 = c2w[4*f], w21 = c2w[4*f+1], w22 = c2w[4*f+2], w23 = c2w[4*f+3];
        float b2f = c2b[f];
        float w30 = c3w[9*f],   w31 = c3w[9*f+1], w32 = c3w[9*f+2];
        float w33 = c3w[9*f+3], w34 = c3w[9*f+4], w35 = c3w[9*f+5];
        float w36 = c3w[9*f+6], w37 = c3w[9*f+7], w38 = c3w[9*f+8];
        float b3f = c3b[f];
#pragma unroll
        for (int i = 0; i < 8; ++i) {
            float v1 = fmaf(w1f, s0[i], b1f);
            m1[i] = fmaxf(m1[i], v1);
            float v2 = b2f;
            v2 = fmaf(w20, s0[i], v2); v2 = fmaf(w21, s0[i+1], v2);
            v2 = fmaf(w22, s1[i], v2); v2 = fmaf(w23, s1[i+1], v2);
            m2[i] = fmaxf(m2[i], v2);
            float v3 = b3f;
            v3 = fmaf(w30, s0[i], v3); v3 = fmaf(w31, s0[i+1], v3); v3 = fmaf(w32, s0[i+2], v3);
            v3 = fmaf(w33, s1[i], v3); v3 = fmaf(w34, s1[i+1], v3); v3 = fmaf(w35, s1[i+2], v3);
            v3 = fmaf(w36, s2[i], v3); v3 = fmaf(w37, s2[i+1], v3); v3 = fmaf(w38, s2[i+2], v3);
            m3[i] = fmaxf(m3[i], v3);
        }
    }

    float a1[3] = {-FLT_MAX, -FLT_MAX, -FLT_MAX};
    float a2[3] = {-FLT_MAX, -FLT_MAX, -FLT_MAX};
#pragma unroll
    for (int i = 0; i < 8; ++i) {
        if (c0 + cb + i < ND) {
            ins2(a1[0], a2[0], fmaxf(m1[i], 0.f));
            ins2(a1[1], a2[1], fmaxf(m2[i], 0.f));
            ins2(a1[2], a2[2], fmaxf(m3[i], 0.f));
        }
    }
    int wv = tid >> 6, lane = tid & 63;
#pragma unroll
    for (int m = 16; m <= 32; m <<= 1) {   // merge the wave's 4 dt per q
#pragma unroll
        for (int ng = 0; ng < 3; ++ng) {
            float b1v = __shfl_xor(a1[ng], m), b2v = __shfl_xor(a2[ng], m);
            merge2(a1[ng], a2[ng], b1v, b2v);
        }
    }
    __shared__ float PART[4][16][6];
    if (lane < 16) {
#pragma unroll
        for (int ng = 0; ng < 3; ++ng) {
            PART[wv][lane][ng * 2]     = a1[ng];
            PART[wv][lane][ng * 2 + 1] = a2[ng];
        }
    }
    __syncthreads();
    if (tid < 16) {
        float* c2p = ws + WS_C2 + ((size_t)(b * NQ + tid) * 3) * 14 + strip * 2;
#pragma unroll
        for (int ng = 0; ng < 3; ++ng) {
            float x1 = PART[0][tid][ng * 2], x2 = PART[0][tid][ng * 2 + 1];
#pragma unroll
            for (int p = 1; p < 4; ++p)
                merge2(x1, x2, PART[p][tid][ng * 2], PART[p][tid][ng * 2 + 1]);
            c2p[ng * 14] = x1; c2p[ng * 14 + 1] = x2;
        }
    }
}

// ------- kctm: ctx prefix-scan + top6 + strip-merge + MLP; grid (NB), 256 -------
__global__ __launch_bounds__(256) void kctm(const float* __restrict__ w1,
                                            const float* __restrict__ b1,
                                            const float* __restrict__ w2,
                                            const float* __restrict__ b2,
                                            const float* __restrict__ w3,
                                            const float* __restrict__ b3,
                                            float* __restrict__ ws,
                                            float* __restrict__ out) {
    int b = blockIdx.x;
    int tid = threadIdx.x;
    int wv = tid >> 6, lane = tid & 63;
    __shared__ float P[4][804];
    __shared__ float sc[208];

    // ---- phase 1: prefix scans (wave wv owns rows 4wv..4wv+3, seq) ----
    const float* simb = ws + WS_SIM + (size_t)b * NQ * ND;
    for (int rr = 0; rr < 4; ++rr) {
        int q = wv * 4 + rr;
        const float* simrow = simb + (size_t)q * ND;
        float carry = 0.f;
        for (int c = 0; c < 13; ++c) {
            int d = c * 64 + lane;
            float v = (d < ND) ? simrow[d] : 0.f;
#pragma unroll
            for (int off = 1; off < 64; off <<= 1) {
                float t = __shfl_up(v, off);
                if (lane >= off) v += t;
            }
            v += carry;
            if (d < ND) P[wv][d] = v;
            carry = __shfl(v, 63);
        }
        __syncthreads();   // P[wv] complete & visible (block-wide, all waves hit)
        // ---- top6 for this row ----
        const float* cinv = ws + WS_CTXINV + (size_t)b * ND;
        float top[6] = {-FLT_MAX,-FLT_MAX,-FLT_MAX,-FLT_MAX,-FLT_MAX,-FLT_MAX};
        for (int c = 0; c < 13; ++c) {
            int d = c * 64 + lane;
            if (d < ND) {
                int hi_i = (d + 3 < ND) ? d + 3 : ND - 1;
                float hi = P[wv][hi_i];
                float lo = (d >= 5) ? P[wv][d - 5] : 0.f;
                float ctx = (hi - lo) * (1.f / 9.f) * cinv[d];
                ins6(top, ctx);
            }
        }
#pragma unroll
        for (int m = 1; m < 64; m <<= 1) {
            float o0 = __shfl_xor(top[0], m), o1 = __shfl_xor(top[1], m);
            float o2 = __shfl_xor(top[2], m), o3 = __shfl_xor(top[3], m);
            float o4 = __shfl_xor(top[4], m), o5 = __shfl_xor(top[5], m);
            ins6(top, o0); ins6(top, o1); ins6(top, o2);
            ins6(top, o3); ins6(top, o4); ins6(top, o5);
        }
        if (lane == 0) {
            sc[q * 13 + 6]  = top[0]; sc[q * 13 + 7]  = top[1];
            sc[q * 13 + 8]  = top[2]; sc[q * 13 + 9]  = top[3];
            sc[q * 13 + 10] = top[4]; sc[q * 13 + 11] = top[5];
        }
        __syncthreads();
    }

    // ---- phase 2: strip merge (tid<48) + idf (tid 48..63) ----
    if (tid < 48) {
        int q = tid / 3, ng = tid % 3;
        const float* p = ws + WS_C2 + ((size_t)(b * NQ + q) * 3 + ng) * 14;
        float x1 = p[0], x2 = p[1];
#pragma unroll
        for (int s = 1; s < 7; ++s) merge2(x1, x2, p[s * 2], p[s * 2 + 1]);
        sc[q * 13 + ng * 2] = x1; sc[q * 13 + ng * 2 + 1] = x2;
    } else if (tid < 64) {
        int q = tid - 48;
        sc[q * 13 + 12] = ws[WS_SCORES + (size_t)(b * NQ + q) * 13 + 12];
    }
    __syncthreads();

    // ---- phase 3: MLP (wave 0 only, barrier-free via shfl) ----
    if (tid < 64) {
        int j = tid & 31, half = tid >> 5;
        float a = 0.f;
        int i0 = half * 104;
        for (int i = 0; i < 104; ++i) a = fmaf(sc[i0 + i], w1[(i0 + i) * 32 + j], a);
        a += __shfl_xor(a, 32);
        a = fmaxf(a + b1[j], 0.f);          // both halves now hold h_j
        float a2v = 0.f;
        for (int k = 0; k < 32; ++k) {
            float hk = __shfl(a, k);        // broadcast h_k
            a2v = fmaf(hk, w2[k * 32 + j], a2v);
        }
        a2v = fmaxf(a2v + b2[j], 0.f);
        float r = a2v * w3[j];
        if (half) r = 0.f;                  // halves are duplicates
#pragma unroll
        for (int m = 1; m <= 32; m <<= 1) r += __shfl_xor(r, m);
        if (tid == 0) out[b] = r + b3[0];
    }
}

extern "C" void kernel_launch(void* const* d_in, const int* in_sizes, int n_in,
                              void* d_out, int out_size, void* d_ws, size_t ws_size,
                              hipStream_t stream) {
    (void)in_sizes; (void)n_in; (void)out_size; (void)ws_size;
    const int*   qrls = (const int*)d_in[0];
    const int*   docw = (const int*)d_in[1];
    const float* emb  = (const float*)d_in[2];
    const float* idf  = (const float*)d_in[3];
    const float* c1w  = (const float*)d_in[4];
    const float* c1b  = (const float*)d_in[5];
    const float* c2w  = (const float*)d_in[6];
    const float* c2b  = (const float*)d_in[7];
    const float* c3w  = (const float*)d_in[8];
    const float* c3b  = (const float*)d_in[9];
    const float* w1   = (const float*)d_in[10];
    const float* b1   = (const float*)d_in[11];
    const float* w2   = (const float*)d_in[12];
    const float* b2   = (const float*)d_in[13];
    const float* w3   = (const float*)d_in[14];
    const float* b3   = (const float*)d_in[15];
    float* ws  = (float*)d_ws;
    float* out = (float*)d_out;

    kq<<<dim3(NB), 256, 0, stream>>>(qrls, emb, idf, ws);
    kfused<<<dim3(25, NB), 256, 0, stream>>>(docw, emb, ws);
    kconv2<<<dim3(7, NB), 256, 0, stream>>>(c1w, c1b, c2w, c2b, c3w, c3b, ws);
    kctm<<<dim3(NB), 256, 0, stream>>>(w1, b1, w2, b2, w3, b3, ws, out);
}

// Round 10
// 121.597 us; speedup vs baseline: 1.5489x; 1.0708x over previous
//
#include <hip/hip_runtime.h>
#include <float.h>
#include <math.h>

#define NB 128
#define NQ 16
#define ND 800
#define NE 300

// workspace layout (float offsets). All regions written every call.
#define WS_SIM    0                          // [NB][NQ][ND] raw dots
#define WS_CTXINV (NB*NQ*ND)                 // [NB][ND] 1/(||ctx||/9+1e-9)
#define WS_SCORES (WS_CTXINV + NB*ND)        // [NB][NQ][13] (slots 6..12 used)
#define WS_C2     (WS_SCORES + NB*NQ*13)     // [NB][NQ][3][25 strips][2]
#define WS_QBF    (WS_C2 + NB*NQ*3*50)       // [NB][16][320] bf16

#define SP 308                                // kfused LDS row pitch (floats)

typedef __attribute__((ext_vector_type(8))) short short8;
typedef __attribute__((ext_vector_type(4))) float f32x4;
typedef __attribute__((ext_vector_type(4))) unsigned short ushort4v;

__device__ __forceinline__ unsigned short f2bf(float x) {   // RNE fp32->bf16
    unsigned u = __float_as_uint(x);
    u += 0x7FFF + ((u >> 16) & 1);
    return (unsigned short)(u >> 16);
}

__device__ __forceinline__ void ins6(float t[6], float v) {
    if (v > t[5]) t[5] = v;
    float a;
    if (t[5] > t[4]) { a = t[4]; t[4] = t[5]; t[5] = a; }
    if (t[4] > t[3]) { a = t[3]; t[3] = t[4]; t[4] = a; }
    if (t[3] > t[2]) { a = t[2]; t[2] = t[3]; t[3] = a; }
    if (t[2] > t[1]) { a = t[1]; t[1] = t[2]; t[2] = a; }
    if (t[1] > t[0]) { a = t[0]; t[0] = t[1]; t[1] = a; }
}

__device__ __forceinline__ void ins2(float& a1, float& a2, float v) {
    if (v > a2) a2 = v;
    if (a2 > a1) { float t = a1; a1 = a2; a2 = t; }
}

__device__ __forceinline__ void merge2(float& a1, float& a2, float b1v, float b2v) {
    float hi = fmaxf(a1, b1v), lo = fminf(a1, b1v);
    a1 = hi;
    a2 = fmaxf(lo, fmaxf(a2, b2v));
}

// ------- kq: q rows -> bf16 [16][320] (K-pad zeroed) + idf -------
__global__ __launch_bounds__(256) void kq(const int* __restrict__ qrls,
                                          const float* __restrict__ emb,
                                          const float* __restrict__ idf,
                                          float* __restrict__ ws) {
    int b = blockIdx.x;
    int tid = threadIdx.x;
    __shared__ int qrow[16];
    if (tid < 16) qrow[tid] = qrls[b * NQ + tid];
    __syncthreads();
    unsigned short* qbf = (unsigned short*)(ws + WS_QBF) + (size_t)b * 16 * 320;
    for (int it = tid; it < 1200; it += 256) {
        int q = it / 75, e4 = it - q * 75;
        float4 v = *(const float4*)(emb + (size_t)qrow[q] * NE + e4 * 4);
        ushort4v u;
        u[0] = f2bf(v.x); u[1] = f2bf(v.y); u[2] = f2bf(v.z); u[3] = f2bf(v.w);
        *(ushort4v*)(qbf + q * 320 + e4 * 4) = u;
    }
    if (tid < 160) {
        int q = tid / 10, p = tid - q * 10;
        *(unsigned*)(qbf + q * 320 + 300 + p * 2) = 0u;
    }
    if (tid < NQ)
        ws[WS_SCORES + (b * NQ + tid) * 13 + 12] = idf[qrow[tid]];
}

// ------- kfused: grid (25, NB), 256 thr = 4 waves -------
// Stage 40 doc rows (32-col tile + halo) fp32 via global_load_lds. Then:
//   waves 0,1: MFMA sim cols base..base+31 (write global + SL)
//   wave 2   : MFMA tile on staged rows 24..39, keep cols 32,33 -> SL
//   wave 3   : ctx-norm, column-rolling window (no slide8 storm)
// Barrier, then all 4 waves: f-outer conv on SL (16q x 34 cols) -> strip top2.
__global__ __launch_bounds__(256, 3) void kfused(const int* __restrict__ docw,
                                                 const float* __restrict__ emb,
                                                 const float* __restrict__ c1w,
                                                 const float* __restrict__ c1b,
                                                 const float* __restrict__ c2w,
                                                 const float* __restrict__ c2b,
                                                 const float* __restrict__ c3w,
                                                 const float* __restrict__ c3b,
                                                 float* __restrict__ ws) {
    int b = blockIdx.y;
    int base = blockIdx.x * 32;
    int tid = threadIdx.x;
    __shared__ float slds[12544];            // staging; later aliased as PART
    __shared__ float SL[18][36];             // sim tile (rows 16,17 zero)
    __shared__ int sidx[40];
    float* PART = slds;                      // [4][16][6] flat, used post-staging

    int wv = tid >> 6, lane = tid & 63;

    if (tid < 40) {
        int rg = base - 4 + tid;
        sidx[tid] = (rg >= 0 && rg < ND) ? docw[b * ND + rg] : -1;
    }
    __syncthreads();

    // ---- async staging: 49 x 1KB ----
    for (int j = wv; j < 49; j += 4) {
        int jj = __builtin_amdgcn_readfirstlane(j);
        int f = jj * 64 + lane;
        int r = f / 77;
        int cs = f - r * 77;
        int rr = (r < 40) ? r : 39;
        int idx = sidx[rr];
        int c = (cs < 75) ? cs : 74;
        const float* gp = emb + (size_t)((idx < 0) ? 0 : idx) * NE + c * 4;
        __builtin_amdgcn_global_load_lds(
            (const __attribute__((address_space(1))) void*)gp,
            (__attribute__((address_space(3))) void*)&slds[jj * 256],
            16, 0, 0);
    }
    __syncthreads();

    // ---- zero col-pads (300..307) and invalid halo rows ----
    float4 z4 = {0.f, 0.f, 0.f, 0.f};
    if (tid < 80) {
        int r = tid >> 1, c = 75 + (tid & 1);
        *(float4*)&slds[r * SP + c * 4] = z4;
    }
    for (int t = tid; t < 3000; t += 256) {
        int r = t / 75;
        if (sidx[r] < 0) {
            int c = t - r * 75;
            *(float4*)&slds[r * SP + c * 4] = z4;
        }
    }
    __syncthreads();

    if (tid < 72) SL[16 + tid / 36][tid % 36] = 0.f;   // conv bottom pad

    int rsub = lane & 15, kgrp = lane >> 4;

    if (wv < 3) {
        // ---- MFMA sim ----
        const unsigned short* qp = (const unsigned short*)(ws + WS_QBF)
                                   + ((size_t)b * 16 + rsub) * 320 + kgrp * 8;
        short8 afr[10];
#pragma unroll
        for (int k = 0; k < 10; ++k)
            afr[k] = *(const short8*)(qp + k * 32);

        int rowoff = (wv == 2) ? 24 : (4 + wv * 16);
        int lrb = (rowoff + rsub) * SP;
        f32x4 acc = {0.f, 0.f, 0.f, 0.f};
#pragma unroll
        for (int k = 0; k < 10; ++k) {
            int c0 = k * 32 + kgrp * 8;
            short8 bf = {0, 0, 0, 0, 0, 0, 0, 0};
            if (c0 < 300) {
                float4 x0 = *(const float4*)&slds[lrb + c0];
                float4 x1 = *(const float4*)&slds[lrb + c0 + 4];
                bf[0] = (short)f2bf(x0.x); bf[1] = (short)f2bf(x0.y);
                bf[2] = (short)f2bf(x0.z); bf[3] = (short)f2bf(x0.w);
                bf[4] = (short)f2bf(x1.x); bf[5] = (short)f2bf(x1.y);
                bf[6] = (short)f2bf(x1.z); bf[7] = (short)f2bf(x1.w);
            }
            acc = __builtin_amdgcn_mfma_f32_16x16x32_bf16(afr[k], bf, acc, 0, 0, 0);
        }
        if (wv < 2) {
            int col = base + wv * 16 + rsub;       // always < 800
            float* simp = ws + WS_SIM + (size_t)b * NQ * ND + col;
#pragma unroll
            for (int i = 0; i < 4; ++i) {
                simp[(size_t)(kgrp * 4 + i) * ND] = acc[i];
                SL[kgrp * 4 + i][wv * 16 + rsub] = acc[i];
            }
        } else if (rsub == 12 || rsub == 13) {     // cols base+32, base+33
#pragma unroll
            for (int i = 0; i < 4; ++i)
                SL[kgrp * 4 + i][32 + (rsub - 12)] = acc[i];
        }
    } else {
        // ---- ctx-norm: rolling 8-row window, lane owns 5 elems ----
        int e0 = lane * 5;
        bool lv = (lane < 61);
        float w0 = 0.f, w1_ = 0.f, w2_ = 0.f, w3_ = 0.f, w4_ = 0.f;
        float keep = 0.f;
        for (int i = 0; i < 39; ++i) {
            if (lv) {
                const float* rp = &slds[i * SP + e0];
                w0 += rp[0]; w1_ += rp[1]; w2_ += rp[2]; w3_ += rp[3]; w4_ += rp[4];
                if (i >= 8) {
                    const float* rq = &slds[(i - 8) * SP + e0];
                    w0 -= rq[0]; w1_ -= rq[1]; w2_ -= rq[2]; w3_ -= rq[3]; w4_ -= rq[4];
                }
            }
            if (i >= 7) {
                float s = lv ? (w0*w0 + w1_*w1_ + w2_*w2_ + w3_*w3_ + w4_*w4_) : 0.f;
                s += __shfl_xor(s, 1);  s += __shfl_xor(s, 2);
                s += __shfl_xor(s, 4);  s += __shfl_xor(s, 8);
                s += __shfl_xor(s, 16); s += __shfl_xor(s, 32);
                if (lane == i - 7) keep = s;
            }
        }
        if (lane < 32)
            ws[WS_CTXINV + b * ND + base + lane] =
                1.f / (sqrtf(keep) * (1.f / 9.f) + 1e-9f);
    }
    __syncthreads();

    // ---- conv phase: thread (q, cg) handles 2 cells at d0 = cg*2 ----
    int q = tid & 15, cg = tid >> 4;
    int d0 = cg * 2;
    float r0[4], r1[4], r2[4];
#pragma unroll
    for (int c = 0; c < 4; ++c) {
        r0[c] = SL[q][d0 + c];
        r1[c] = SL[q + 1][d0 + c];
        r2[c] = SL[q + 2][d0 + c];
    }
    float m1[2] = {-FLT_MAX, -FLT_MAX};
    float m2[2] = {-FLT_MAX, -FLT_MAX};
    float m3[2] = {-FLT_MAX, -FLT_MAX};
    for (int f = 0; f < 32; ++f) {
        float w1f = c1w[f], b1f = c1b[f];
        float w20 = c2w[4*f], w21 = c2w[4*f+1], w22 = c2w[4*f+2], w23 = c2w[4*f+3];
        float b2f = c2b[f];
        float w30 = c3w[9*f],   w31 = c3w[9*f+1], w32 = c3w[9*f+2];
        float w33 = c3w[9*f+3], w34 = c3w[9*f+4], w35 = c3w[9*f+5];
        float w36 = c3w[9*f+6], w37 = c3w[9*f+7], w38 = c3w[9*f+8];
        float b3f = c3b[f];
#pragma unroll
        for (int i = 0; i < 2; ++i) {
            float v1 = fmaf(w1f, r0[i], b1f);
            m1[i] = fmaxf(m1[i], v1);
            float v2 = b2f;
            v2 = fmaf(w20, r0[i], v2); v2 = fmaf(w21, r0[i+1], v2);
            v2 = fmaf(w22, r1[i], v2); v2 = fmaf(w23, r1[i+1], v2);
            m2[i] = fmaxf(m2[i], v2);
            float v3 = b3f;
            v3 = fmaf(w30, r0[i], v3); v3 = fmaf(w31, r0[i+1], v3); v3 = fmaf(w32, r0[i+2], v3);
            v3 = fmaf(w33, r1[i], v3); v3 = fmaf(w34, r1[i+1], v3); v3 = fmaf(w35, r1[i+2], v3);
            v3 = fmaf(w36, r2[i], v3); v3 = fmaf(w37, r2[i+1], v3); v3 = fmaf(w38, r2[i+2], v3);
            m3[i] = fmaxf(m3[i], v3);
        }
    }
    float a1[3] = {-FLT_MAX, -FLT_MAX, -FLT_MAX};
    float a2[3] = {-FLT_MAX, -FLT_MAX, -FLT_MAX};
#pragma unroll
    for (int i = 0; i < 2; ++i) {
        ins2(a1[0], a2[0], fmaxf(m1[i], 0.f));
        ins2(a1[1], a2[1], fmaxf(m2[i], 0.f));
        ins2(a1[2], a2[2], fmaxf(m3[i], 0.f));
    }
#pragma unroll
    for (int m = 16; m <= 32; m <<= 1) {   // merge the wave's 4 cg per q
#pragma unroll
        for (int ng = 0; ng < 3; ++ng) {
            float b1v = __shfl_xor(a1[ng], m), b2v = __shfl_xor(a2[ng], m);
            merge2(a1[ng], a2[ng], b1v, b2v);
        }
    }
    if (lane < 16) {                        // staging LDS is dead -> PART alias
#pragma unroll
        for (int ng = 0; ng < 3; ++ng) {
            PART[(wv * 16 + lane) * 6 + ng * 2]     = a1[ng];
            PART[(wv * 16 + lane) * 6 + ng * 2 + 1] = a2[ng];
        }
    }
    __syncthreads();
    if (tid < 16) {
        float* c2p = ws + WS_C2 + ((size_t)(b * NQ + tid) * 3) * 50 + blockIdx.x * 2;
#pragma unroll
        for (int ng = 0; ng < 3; ++ng) {
            float x1 = PART[tid * 6 + ng * 2], x2 = PART[tid * 6 + ng * 2 + 1];
#pragma unroll
            for (int p = 1; p < 4; ++p)
                merge2(x1, x2, PART[(p * 16 + tid) * 6 + ng * 2],
                               PART[(p * 16 + tid) * 6 + ng * 2 + 1]);
            c2p[ng * 50] = x1; c2p[ng * 50 + 1] = x2;
        }
    }
}

// ------- kscan: prefix scan of raw dots -> context cosine -> top-6 -------
__global__ __launch_bounds__(256) void kscan(float* __restrict__ ws) {
    int b = blockIdx.y;
    int w = threadIdx.x >> 6, lane = threadIdx.x & 63;
    int q = blockIdx.x * 4 + w;
    __shared__ float P[4][ND];
    const float* simrow = ws + WS_SIM + (size_t)(b * NQ + q) * ND;
    const float* cinv = ws + WS_CTXINV + b * ND;
    float carry = 0.f;
    for (int c = 0; c < 13; ++c) {
        int d = c * 64 + lane;
        float v = (d < ND) ? simrow[d] : 0.f;
#pragma unroll
        for (int off = 1; off < 64; off <<= 1) {
            float t = __shfl_up(v, off);
            if (lane >= off) v += t;
        }
        v += carry;
        if (d < ND) P[w][d] = v;
        carry = __shfl(v, 63);
    }
    __syncthreads();
    float top[6] = {-FLT_MAX,-FLT_MAX,-FLT_MAX,-FLT_MAX,-FLT_MAX,-FLT_MAX};
    for (int c = 0; c < 13; ++c) {
        int d = c * 64 + lane;
        if (d < ND) {
            int hi_i = (d + 3 < ND) ? d + 3 : ND - 1;
            float hi = P[w][hi_i];
            float lo = (d >= 5) ? P[w][d - 5] : 0.f;
            float ctx = (hi - lo) * (1.f / 9.f) * cinv[d];
            ins6(top, ctx);
        }
    }
#pragma unroll
    for (int m = 1; m < 64; m <<= 1) {
        float o0 = __shfl_xor(top[0], m), o1 = __shfl_xor(top[1], m);
        float o2 = __shfl_xor(top[2], m), o3 = __shfl_xor(top[3], m);
        float o4 = __shfl_xor(top[4], m), o5 = __shfl_xor(top[5], m);
        ins6(top, o0); ins6(top, o1); ins6(top, o2);
        ins6(top, o3); ins6(top, o4); ins6(top, o5);
    }
    if (lane == 0) {
        float* sc = ws + WS_SCORES + (size_t)(b * NQ + q) * 13;
        sc[6] = top[0]; sc[7] = top[1]; sc[8]  = top[2];
        sc[9] = top[3]; sc[10] = top[4]; sc[11] = top[5];
    }
}

// ------- kmlp: 25-strip merge + scores gather + 208->32->32->1 -------
__global__ __launch_bounds__(64) void kmlp(const float* __restrict__ w1,
                                           const float* __restrict__ b1,
                                           const float* __restrict__ w2,
                                           const float* __restrict__ b2,
                                           const float* __restrict__ w3,
                                           const float* __restrict__ b3,
                                           const float* __restrict__ ws,
                                           float* __restrict__ out) {
    int b = blockIdx.x, tid = threadIdx.x;
    __shared__ float sc[208];
    const float* s = ws + WS_SCORES + (size_t)b * 208;
    for (int i = tid; i < 208; i += 64)
        if ((i % 13) >= 6) sc[i] = s[i];            // slots 6..12
    if (tid < 48) {                                  // slots 0..5 from C2
        int q = tid / 3, ng = tid % 3;
        const float* p = ws + WS_C2 + ((size_t)(b * NQ + q) * 3 + ng) * 50;
        float x1 = p[0], x2 = p[1];
#pragma unroll
        for (int st = 1; st < 25; ++st) merge2(x1, x2, p[st * 2], p[st * 2 + 1]);
        sc[q * 13 + ng * 2] = x1; sc[q * 13 + ng * 2 + 1] = x2;
    }
    __syncthreads();
    int j = tid & 31, half = tid >> 5;
    float a = 0.f;
    int i0 = half * 104;
    for (int i = 0; i < 104; ++i) a = fmaf(sc[i0 + i], w1[(i0 + i) * 32 + j], a);
    a += __shfl_xor(a, 32);
    a = fmaxf(a + b1[j], 0.f);                       // both halves hold h_j
    float a2v = 0.f;
    for (int k = 0; k < 32; ++k) {
        float hk = __shfl(a, k);
        a2v = fmaf(hk, w2[k * 32 + j], a2v);
    }
    a2v = fmaxf(a2v + b2[j], 0.f);
    float r = a2v * w3[j];
    if (half) r = 0.f;
#pragma unroll
    for (int m = 1; m <= 32; m <<= 1) r += __shfl_xor(r, m);
    if (tid == 0) out[b] = r + b3[0];
}

extern "C" void kernel_launch(void* const* d_in, const int* in_sizes, int n_in,
                              void* d_out, int out_size, void* d_ws, size_t ws_size,
                              hipStream_t stream) {
    (void)in_sizes; (void)n_in; (void)out_size; (void)ws_size;
    const int*   qrls = (const int*)d_in[0];
    const int*   docw = (const int*)d_in[1];
    const float* emb  = (const float*)d_in[2];
    const float* idf  = (const float*)d_in[3];
    const float* c1w  = (const float*)d_in[4];
    const float* c1b  = (const float*)d_in[5];
    const float* c2w  = (const float*)d_in[6];
    const float* c2b  = (const float*)d_in[7];
    const float* c3w  = (const float*)d_in[8];
    const float* c3b  = (const float*)d_in[9];
    const float* w1   = (const float*)d_in[10];
    const float* b1   = (const float*)d_in[11];
    const float* w2   = (const float*)d_in[12];
    const float* b2   = (const float*)d_in[13];
    const float* w3   = (const float*)d_in[14];
    const float* b3   = (const float*)d_in[15];
    float* ws  = (float*)d_ws;
    float* out = (float*)d_out;

    kq<<<dim3(NB), 256, 0, stream>>>(qrls, emb, idf, ws);
    kfused<<<dim3(25, NB), 256, 0, stream>>>(docw, emb,
                                             c1w, c1b, c2w, c2b, c3w, c3b, ws);
    kscan<<<dim3(4, NB), 256, 0, stream>>>(ws);
    kmlp<<<dim3(NB), 64, 0, stream>>>(w1, b1, w2, b2, w3, b3, ws, out);
}